// Round 6
// baseline (439.511 us; speedup 1.0000x reference)
//
#include <hip/hip_runtime.h>
#include <hip/hip_cooperative_groups.h>

namespace cg = cooperative_groups;

typedef unsigned short u16;
typedef unsigned int u32;
typedef __attribute__((ext_vector_type(8))) short sh8;
typedef __attribute__((ext_vector_type(4))) float f32x4;
typedef __attribute__((ext_vector_type(4))) unsigned short us4;

__device__ __forceinline__ float bf2f(u16 u) {
  union { u32 i; float f; } x; x.i = ((u32)u) << 16; return x.f;
}
__device__ __forceinline__ u16 f2bf(float f) {
  union { float f; u32 i; } x; x.f = f;
  u32 u = x.i;
  u32 r = (u + 0x7FFFu + ((u >> 16) & 1u)) >> 16;
  return (u16)r;
}

__device__ __forceinline__ sh8 load8f_nt(const float* p, size_t off) {
  const f32x4* f = (const f32x4*)(p + off);
  f32x4 x = __builtin_nontemporal_load(f);
  f32x4 y = __builtin_nontemporal_load(f + 1);
  sh8 r;
  r[0] = (short)f2bf(x[0]); r[1] = (short)f2bf(x[1]);
  r[2] = (short)f2bf(x[2]); r[3] = (short)f2bf(x[3]);
  r[4] = (short)f2bf(y[0]); r[5] = (short)f2bf(y[1]);
  r[6] = (short)f2bf(y[2]); r[7] = (short)f2bf(y[3]);
  return r;
}

// ---------------- prep: internal bf16 weights (transposed + fused) ----------
__global__ void k_prep(const float* __restrict__ Ws, const float* __restrict__ Wn,
                       const float* __restrict__ Wm, const float* __restrict__ Wg,
                       const float* __restrict__ b_sage, const float* __restrict__ bg,
                       const float* __restrict__ bm, const float* __restrict__ ln_g,
                       const float* __restrict__ ln_b,
                       u16* __restrict__ WmT, u16* __restrict__ WsT, u16* __restrict__ WnT,
                       u16* __restrict__ WsgT, u16* __restrict__ WngT, u16* __restrict__ WgBT,
                       float* __restrict__ bm_f, float* __restrict__ lng_f,
                       float* __restrict__ lnb_f, float* __restrict__ bsage_f,
                       float* __restrict__ bsg) {
  int idx = blockIdx.x * blockDim.x + threadIdx.x;
  int stride = gridDim.x * blockDim.x;
  for (int i = idx; i < 32768; i += stride) {
    int n = i >> 8, k = i & 255;
    WmT[n * 256 + k] = f2bf(Wm[k * 128 + n]);
  }
  for (int i = idx; i < 16384; i += stride) {
    int n = i >> 7, k = i & 127;
    WsT[i] = f2bf(Ws[k * 128 + n]);
    WnT[i] = f2bf(Wn[k * 128 + n]);
    WgBT[i] = f2bf(Wg[(128 + k) * 128 + n]);
  }
  for (int i = idx; i < 16384; i += stride) {
    int c = i >> 7, k = i & 127;
    float s1 = 0.f, s2 = 0.f;
    for (int j = 0; j < 128; ++j) {
      float wg = Wg[j * 128 + c];
      s1 += Ws[k * 128 + j] * wg;
      s2 += Wn[k * 128 + j] * wg;
    }
    WsgT[c * 128 + k] = f2bf(s1);
    WngT[c * 128 + k] = f2bf(s2);
  }
  for (int i = idx; i < 128; i += stride) {
    bm_f[i] = bm[i];
    lng_f[i] = ln_g[i];
    lnb_f[i] = ln_b[i];
    bsage_f[i] = b_sage[i];
    float s = bg[i];
    for (int j = 0; j < 128; ++j) s += b_sage[j] * Wg[j * 128 + i];
    bsg[i] = s;
  }
}

// ---------------- CSR build: single cooperative kernel (R6) -----------------
// Replaces k_count + k_scan1/2/3 + k_perm (5 launches + 4 gaps/tails -> 1).
// cnt must be zeroed before launch. Grid 512x256 (co-resident trivially).
__global__ __launch_bounds__(256) void k_csr(
    const int* __restrict__ src, const int* __restrict__ dst,
    int* __restrict__ cnt, int* __restrict__ rowptr, int* __restrict__ cursor,
    int* __restrict__ bsum, int* __restrict__ src_sorted, int N, int E) {
  cg::grid_group grid = cg::this_grid();
  int tid = threadIdx.x, bid = blockIdx.x;
  int gsz = gridDim.x * 256;
  int gidx = bid * 256 + tid;
  // phase 1: degree count
  for (int e = gidx; e < E; e += gsz) atomicAdd(&cnt[dst[e]], 1);
  grid.sync();
  // phase 2: per-256-chunk sums
  int NB = (N + 255) >> 8;
  {
    __shared__ int ws[4];
    for (int c = bid; c < NB; c += gridDim.x) {
      int i = c * 256 + tid;
      int v = (i < N) ? cnt[i] : 0;
#pragma unroll
      for (int m = 1; m < 64; m <<= 1) v += __shfl_xor(v, m, 64);
      if ((tid & 63) == 0) ws[tid >> 6] = v;
      __syncthreads();
      if (tid == 0) bsum[c] = ws[0] + ws[1] + ws[2] + ws[3];
      __syncthreads();
    }
  }
  grid.sync();
  // phase 3: rowptr/cursor via chunk-prefix (sum bsum[0..c)) + intra-chunk scan
  {
    __shared__ int ws2[4];
    __shared__ int s[256];
    for (int c = bid; c < NB; c += gridDim.x) {
      int base = 0;
      for (int j = tid; j < c; j += 256) base += bsum[j];
#pragma unroll
      for (int m = 1; m < 64; m <<= 1) base += __shfl_xor(base, m, 64);
      if ((tid & 63) == 0) ws2[tid >> 6] = base;
      __syncthreads();
      base = ws2[0] + ws2[1] + ws2[2] + ws2[3];
      int i = c * 256 + tid;
      int v = (i < N) ? cnt[i] : 0;
      s[tid] = v;
      __syncthreads();
      for (int off = 1; off < 256; off <<= 1) {
        int x = (tid >= off) ? s[tid - off] : 0;
        __syncthreads();
        s[tid] += x;
        __syncthreads();
      }
      int excl = base + s[tid] - v;
      if (i < N) {
        rowptr[i] = excl;
        cursor[i] = excl;
        if (i == N - 1) rowptr[N] = excl + v;
      }
      __syncthreads();
    }
  }
  grid.sync();
  // phase 4: permutation scatter
  for (int e = gidx; e < E; e += gsz) {
    int p = atomicAdd(&cursor[dst[e]], 1);
    src_sorted[p] = src[e];
  }
}

// ---------------- node MLP: M = relu(LN(concat(h,ctx)@Wm + bm)) -------------
// R3 structure (verified): weights in VGPRs (A), node tile in 8KB LDS (B).
__global__ __launch_bounds__(512) void k_node(
    const float* __restrict__ h, const float* __restrict__ ctx,
    const u16* __restrict__ WmT, const float* __restrict__ bm_f,
    const float* __restrict__ lng_f, const float* __restrict__ lnb_f,
    u16* __restrict__ hm, int N) {
  __shared__ u16 atile[16 * 256];
  __shared__ u16 mtile[16 * 128];
  __shared__ float scr[8 * 16 * 2];
  int tid = threadIdx.x;
  int lane = tid & 63;
  int wave = tid >> 6;
  int col16 = lane & 15;
  int quad = lane >> 4;

  sh8 areg[8];
#pragma unroll
  for (int ks = 0; ks < 8; ++ks)
    areg[ks] = *(const sh8*)&WmT[(size_t)(wave * 16 + col16) * 256 + ks * 32 + quad * 8];

  float bmv[4], gv[4], bv[4];
#pragma unroll
  for (int r = 0; r < 4; ++r) {
    int c = wave * 16 + quad * 4 + r;
    bmv[r] = bm_f[c]; gv[r] = lng_f[c]; bv[r] = lnb_f[c];
  }

  int srow = tid >> 5;
  int c8 = tid & 31;
  int TT = (N + 15) >> 4;
  for (int tile = blockIdx.x; tile < TT; tile += gridDim.x) {
    int n0 = tile * 16;
    {
      int node = min(n0 + srow, N - 1);
      sh8 a = (c8 < 16) ? load8f_nt(h, (size_t)node * 128 + c8 * 8)
                        : load8f_nt(ctx, (size_t)node * 128 + (c8 - 16) * 8);
      *(sh8*)&atile[srow * 256 + ((c8 ^ (srow & 7)) << 3)] = a;
      if (c8 < 16 && n0 + srow < N)
        __builtin_nontemporal_store(a, (sh8*)&hm[(size_t)(n0 + srow) * 256 + c8 * 8]);
    }
    __syncthreads();
    f32x4 acc = (f32x4)0.0f;
#pragma unroll
    for (int ks = 0; ks < 8; ++ks) {
      int chunk = ks * 4 + quad;
      sh8 b = *(const sh8*)&atile[col16 * 256 + ((chunk ^ (col16 & 7)) << 3)];
      acc = __builtin_amdgcn_mfma_f32_16x16x32_bf16(areg[ks], b, acc, 0, 0, 0);
    }
    float v[4], s1 = 0.f, s2 = 0.f;
#pragma unroll
    for (int r = 0; r < 4; ++r) {
      v[r] = acc[r] + bmv[r];
      s1 += v[r]; s2 += v[r] * v[r];
    }
    s1 += __shfl_xor(s1, 16, 64); s2 += __shfl_xor(s2, 16, 64);
    s1 += __shfl_xor(s1, 32, 64); s2 += __shfl_xor(s2, 32, 64);
    if (lane < 16) {
      scr[(wave * 16 + lane) * 2 + 0] = s1;
      scr[(wave * 16 + lane) * 2 + 1] = s2;
    }
    __syncthreads();
    float t1 = 0.f, t2 = 0.f;
#pragma unroll
    for (int w2 = 0; w2 < 8; ++w2) {
      t1 += scr[(w2 * 16 + col16) * 2 + 0];
      t2 += scr[(w2 * 16 + col16) * 2 + 1];
    }
    float mu = t1 * (1.f / 128.f);
    float var = t2 * (1.f / 128.f) - mu * mu;
    float rstd = rsqrtf(fmaxf(var, 0.f) + 1e-5f);
    us4 pk;
#pragma unroll
    for (int r = 0; r < 4; ++r) {
      float x = (v[r] - mu) * rstd * gv[r] + bv[r];
      x = x > 0.f ? x : 0.f;
      pk[r] = f2bf(x);
    }
    *(us4*)&mtile[col16 * 128 + wave * 16 + quad * 4] = pk;
    __syncthreads();
    if (tid < 256) {
      int row = tid >> 4, ch = tid & 15;
      if (n0 + row < N) {
        sh8 mv = *(const sh8*)&mtile[row * 128 + ch * 8];
        __builtin_nontemporal_store(mv, (sh8*)&hm[(size_t)(n0 + row) * 256 + 128 + ch * 8]);
      }
    }
  }
}

// ---------------- per-node aggregation over hm rows -------------------------
// R6: 8-edge blocks issue 4 independent sh8 gathers in one basic block
// (guaranteed co-in-flight) -> tests whether wave-ILP or MSHR cap binds.
__global__ __launch_bounds__(256) void k_agg(
    const u16* __restrict__ hm, const int* __restrict__ rowptr,
    const int* __restrict__ src_sorted,
    u16* __restrict__ nm, u16* __restrict__ cagg, int N) {
  int gw = (blockIdx.x * 256 + threadIdx.x) >> 6;
  int lane = threadIdx.x & 63;
  int half = lane >> 5;
  int cl = lane & 31;
  int tw = (gridDim.x * 256) >> 6;
  for (int n = gw; n < N; n += tw) {
    int b = rowptr[n], e = rowptr[n + 1];
    float a0 = 0.f, a1 = 0.f, a2 = 0.f, a3 = 0.f;
    float a4 = 0.f, a5 = 0.f, a6 = 0.f, a7 = 0.f;
    int i = b;
    for (; i + 8 <= e; i += 8) {
      int s0 = src_sorted[i + half];
      int s1 = src_sorted[i + 2 + half];
      int s2 = src_sorted[i + 4 + half];
      int s3 = src_sorted[i + 6 + half];
      sh8 v0 = *(const sh8*)(hm + (size_t)s0 * 256 + (cl << 3));
      sh8 v1 = *(const sh8*)(hm + (size_t)s1 * 256 + (cl << 3));
      sh8 v2 = *(const sh8*)(hm + (size_t)s2 * 256 + (cl << 3));
      sh8 v3 = *(const sh8*)(hm + (size_t)s3 * 256 + (cl << 3));
      a0 += bf2f((u16)v0[0]) + bf2f((u16)v1[0]) + bf2f((u16)v2[0]) + bf2f((u16)v3[0]);
      a1 += bf2f((u16)v0[1]) + bf2f((u16)v1[1]) + bf2f((u16)v2[1]) + bf2f((u16)v3[1]);
      a2 += bf2f((u16)v0[2]) + bf2f((u16)v1[2]) + bf2f((u16)v2[2]) + bf2f((u16)v3[2]);
      a3 += bf2f((u16)v0[3]) + bf2f((u16)v1[3]) + bf2f((u16)v2[3]) + bf2f((u16)v3[3]);
      a4 += bf2f((u16)v0[4]) + bf2f((u16)v1[4]) + bf2f((u16)v2[4]) + bf2f((u16)v3[4]);
      a5 += bf2f((u16)v0[5]) + bf2f((u16)v1[5]) + bf2f((u16)v2[5]) + bf2f((u16)v3[5]);
      a6 += bf2f((u16)v0[6]) + bf2f((u16)v1[6]) + bf2f((u16)v2[6]) + bf2f((u16)v3[6]);
      a7 += bf2f((u16)v0[7]) + bf2f((u16)v1[7]) + bf2f((u16)v2[7]) + bf2f((u16)v3[7]);
    }
    for (; i + 4 <= e; i += 4) {
      int s0 = src_sorted[i + half];
      int s1 = src_sorted[i + 2 + half];
      sh8 v0 = *(const sh8*)(hm + (size_t)s0 * 256 + (cl << 3));
      sh8 v1 = *(const sh8*)(hm + (size_t)s1 * 256 + (cl << 3));
      a0 += bf2f((u16)v0[0]) + bf2f((u16)v1[0]);
      a1 += bf2f((u16)v0[1]) + bf2f((u16)v1[1]);
      a2 += bf2f((u16)v0[2]) + bf2f((u16)v1[2]);
      a3 += bf2f((u16)v0[3]) + bf2f((u16)v1[3]);
      a4 += bf2f((u16)v0[4]) + bf2f((u16)v1[4]);
      a5 += bf2f((u16)v0[5]) + bf2f((u16)v1[5]);
      a6 += bf2f((u16)v0[6]) + bf2f((u16)v1[6]);
      a7 += bf2f((u16)v0[7]) + bf2f((u16)v1[7]);
    }
    for (; i + 2 <= e; i += 2) {
      int s0 = src_sorted[i + half];
      sh8 v0 = *(const sh8*)(hm + (size_t)s0 * 256 + (cl << 3));
      a0 += bf2f((u16)v0[0]); a1 += bf2f((u16)v0[1]);
      a2 += bf2f((u16)v0[2]); a3 += bf2f((u16)v0[3]);
      a4 += bf2f((u16)v0[4]); a5 += bf2f((u16)v0[5]);
      a6 += bf2f((u16)v0[6]); a7 += bf2f((u16)v0[7]);
    }
    if (i < e && half == 0) {
      int s0 = src_sorted[i];
      sh8 v0 = *(const sh8*)(hm + (size_t)s0 * 256 + (cl << 3));
      a0 += bf2f((u16)v0[0]); a1 += bf2f((u16)v0[1]);
      a2 += bf2f((u16)v0[2]); a3 += bf2f((u16)v0[3]);
      a4 += bf2f((u16)v0[4]); a5 += bf2f((u16)v0[5]);
      a6 += bf2f((u16)v0[6]); a7 += bf2f((u16)v0[7]);
    }
    a0 += __shfl_xor(a0, 32, 64); a1 += __shfl_xor(a1, 32, 64);
    a2 += __shfl_xor(a2, 32, 64); a3 += __shfl_xor(a3, 32, 64);
    a4 += __shfl_xor(a4, 32, 64); a5 += __shfl_xor(a5, 32, 64);
    a6 += __shfl_xor(a6, 32, 64); a7 += __shfl_xor(a7, 32, 64);
    if (half == 0) {
      float inv = (e > b) ? 1.f / (float)(e - b) : 0.f;
      sh8 p;
      p[0] = (short)f2bf(a0 * inv); p[1] = (short)f2bf(a1 * inv);
      p[2] = (short)f2bf(a2 * inv); p[3] = (short)f2bf(a3 * inv);
      p[4] = (short)f2bf(a4 * inv); p[5] = (short)f2bf(a5 * inv);
      p[6] = (short)f2bf(a6 * inv); p[7] = (short)f2bf(a7 * inv);
      if (cl < 16)
        *(sh8*)(nm + (size_t)n * 128 + (cl << 3)) = p;
      else
        *(sh8*)(cagg + (size_t)n * 128 + ((cl - 16) << 3)) = p;
    }
  }
}

// ---------------- fused node GEMMs + gate + blend (4-way col-split) ---------
__global__ __launch_bounds__(256, 3) void k_out(
    const u16* __restrict__ hm, const u16* __restrict__ nm, const u16* __restrict__ cagg,
    const u16* __restrict__ WsT, const u16* __restrict__ WnT,
    const u16* __restrict__ WsgT, const u16* __restrict__ WngT, const u16* __restrict__ WgBT,
    const float* __restrict__ bsage_f, const float* __restrict__ bsg,
    float* __restrict__ out, int N) {
  __shared__ u16 blds[5 * 32 * 128];  // 40 KB
  int tid = threadIdx.x;
  int q = blockIdx.x & 3;
  {
    const u16* matp[5] = {WsT, WnT, WsgT, WngT, WgBT};
#pragma unroll
    for (int m = 0; m < 5; ++m) {
#pragma unroll
      for (int j = 0; j < 2; ++j) {
        int f = tid + j * 256;
        int lc = f >> 4, kc = f & 15;
        int kcs = kc ^ (lc & 15);
        *(sh8*)&blds[(m * 32 + lc) * 128 + kcs * 8] =
            *(const sh8*)&matp[m][(size_t)(q * 32 + lc) * 128 + kc * 8];
      }
    }
  }
  __syncthreads();
  int lane = tid & 63;
  int wave = tid >> 6;
  int col = lane & 15, quad = lane >> 4;
  float bsv[2], bgv[2];
#pragma unroll
  for (int tt = 0; tt < 2; ++tt) {
    int gc = q * 32 + tt * 16 + col;
    bsv[tt] = bsage_f[gc];
    bgv[tt] = bsg[gc];
  }
  int TT = (N + 15) >> 4;
  int slots = (gridDim.x >> 2) * 4;
  for (int tile = (blockIdx.x >> 2) * 4 + wave; tile < TT; tile += slots) {
    int nr = min(tile * 16 + col, N - 1);
    f32x4 as[2], ag[2];
#pragma unroll
    for (int tt = 0; tt < 2; ++tt) {
      as[tt] = (f32x4)0.0f;
      ag[tt] = (f32x4)0.0f;
    }
#pragma unroll 1
    for (int ks = 0; ks < 4; ++ks) {
      int k = ks * 32 + quad * 8;
      sh8 ah = *(const sh8*)&hm[(size_t)nr * 256 + k];
      sh8 am = *(const sh8*)&nm[(size_t)nr * 128 + k];
      sh8 ac = *(const sh8*)&cagg[(size_t)nr * 128 + k];
      int kcs8 = ((ks * 4 + quad) ^ col) * 8;
#pragma unroll
      for (int tt = 0; tt < 2; ++tt) {
        int lc = tt * 16 + col;
        sh8 b1 = *(const sh8*)&blds[(0 * 32 + lc) * 128 + kcs8];
        sh8 b2 = *(const sh8*)&blds[(1 * 32 + lc) * 128 + kcs8];
        sh8 b3 = *(const sh8*)&blds[(2 * 32 + lc) * 128 + kcs8];
        sh8 b4 = *(const sh8*)&blds[(3 * 32 + lc) * 128 + kcs8];
        sh8 b5 = *(const sh8*)&blds[(4 * 32 + lc) * 128 + kcs8];
        as[tt] = __builtin_amdgcn_mfma_f32_16x16x32_bf16(ah, b1, as[tt], 0, 0, 0);
        as[tt] = __builtin_amdgcn_mfma_f32_16x16x32_bf16(am, b2, as[tt], 0, 0, 0);
        ag[tt] = __builtin_amdgcn_mfma_f32_16x16x32_bf16(ah, b3, ag[tt], 0, 0, 0);
        ag[tt] = __builtin_amdgcn_mfma_f32_16x16x32_bf16(am, b4, ag[tt], 0, 0, 0);
        ag[tt] = __builtin_amdgcn_mfma_f32_16x16x32_bf16(ac, b5, ag[tt], 0, 0, 0);
      }
    }
#pragma unroll
    for (int r = 0; r < 4; ++r) {
      int n = tile * 16 + quad * 4 + r;
      if (n < N) {
#pragma unroll
        for (int tt = 0; tt < 2; ++tt) {
          int gc = q * 32 + tt * 16 + col;
          float sv = as[tt][r] + bsv[tt];
          float gl = ag[tt][r] + bgv[tt];
          float g = 1.f / (1.f + __expf(-gl));
          float ca = bf2f(cagg[(size_t)n * 128 + gc]);
          __builtin_nontemporal_store(g * sv + (1.f - g) * ca,
                                      &out[(size_t)n * 128 + gc]);
        }
      }
    }
  }
}

extern "C" void kernel_launch(void* const* d_in, const int* in_sizes, int n_in,
                              void* d_out, int out_size, void* d_ws, size_t ws_size,
                              hipStream_t stream) {
  const float* h = (const float*)d_in[0];
  const float* ctx = (const float*)d_in[1];
  const int* src = (const int*)d_in[2];
  const int* dst = (const int*)d_in[3];
  const float* Ws = (const float*)d_in[4];
  const float* Wn = (const float*)d_in[5];
  const float* b_sage = (const float*)d_in[6];
  const float* Wm = (const float*)d_in[7];
  const float* bm = (const float*)d_in[8];
  const float* ln_g = (const float*)d_in[9];
  const float* ln_b = (const float*)d_in[10];
  const float* Wg = (const float*)d_in[11];
  const float* bg = (const float*)d_in[12];
  int N = in_sizes[0] / 128;
  int E = in_sizes[2];

  char* w = (char*)d_ws;
  auto carve = [&](size_t bytes) {
    char* p = w;
    w += (bytes + 255) & ~(size_t)255;
    return p;
  };
  int* cnt = (int*)carve((size_t)N * 4);
  int* rowptr = (int*)carve((size_t)(N + 1) * 4);
  int* cursor = (int*)carve((size_t)N * 4);
  int* src_sorted = (int*)carve((size_t)E * 4);
  int NB = (N + 255) / 256;
  int* bsum = (int*)carve((size_t)NB * 4);
  u16* WmT = (u16*)carve(32768 * 2);
  u16* WsT = (u16*)carve(16384 * 2);
  u16* WnT = (u16*)carve(16384 * 2);
  u16* WsgT = (u16*)carve(16384 * 2);
  u16* WngT = (u16*)carve(16384 * 2);
  u16* WgBT = (u16*)carve(16384 * 2);
  float* bm_f = (float*)carve(128 * 4);
  float* lng_f = (float*)carve(128 * 4);
  float* lnb_f = (float*)carve(128 * 4);
  float* bsage_f = (float*)carve(128 * 4);
  float* bsg = (float*)carve(128 * 4);
  u16* hm = (u16*)carve((size_t)N * 256 * 2);
  u16* nm = (u16*)carve((size_t)N * 128 * 2);
  u16* cagg = (u16*)carve((size_t)N * 128 * 2);

  hipMemsetAsync(cnt, 0, (size_t)N * 4, stream);
  k_prep<<<128, 256, 0, stream>>>(Ws, Wn, Wm, Wg, b_sage, bg, bm, ln_g, ln_b,
                                  WmT, WsT, WnT, WsgT, WngT, WgBT,
                                  bm_f, lng_f, lnb_f, bsage_f, bsg);
  {
    // cooperative CSR build (count -> scan -> perm), 1 launch replaces 5
    void* args[] = {(void*)&src, (void*)&dst, (void*)&cnt, (void*)&rowptr,
                    (void*)&cursor, (void*)&bsum, (void*)&src_sorted,
                    (void*)&N, (void*)&E};
    hipLaunchCooperativeKernel((void*)k_csr, dim3(512), dim3(256), args, 0, stream);
  }
  int TT = (N + 15) / 16;
  int gn = TT < 1024 ? TT : 1024;
  k_node<<<gn, 512, 0, stream>>>(h, ctx, WmT, bm_f, lng_f, lnb_f, hm, N);
  k_agg<<<4096, 256, 0, stream>>>(hm, rowptr, src_sorted, nm, cagg, N);
  k_out<<<1024, 256, 0, stream>>>(hm, nm, cagg, WsT, WnT, WsgT, WngT, WgBT,
                                  bsage_f, bsg, (float*)d_out, N);
}

// Round 7
// 253.899 us; speedup vs baseline: 1.7311x; 1.7311x over previous
//
#include <hip/hip_runtime.h>

typedef unsigned short u16;
typedef unsigned int u32;
typedef __attribute__((ext_vector_type(8))) short sh8;
typedef __attribute__((ext_vector_type(4))) float f32x4;
typedef __attribute__((ext_vector_type(4))) unsigned short us4;

__device__ __forceinline__ float bf2f(u16 u) {
  union { u32 i; float f; } x; x.i = ((u32)u) << 16; return x.f;
}
__device__ __forceinline__ u16 f2bf(float f) {
  union { float f; u32 i; } x; x.f = f;
  u32 u = x.i;
  u32 r = (u + 0x7FFFu + ((u >> 16) & 1u)) >> 16;
  return (u16)r;
}

__device__ __forceinline__ sh8 load8f_nt(const float* p, size_t off) {
  const f32x4* f = (const f32x4*)(p + off);
  f32x4 x = __builtin_nontemporal_load(f);
  f32x4 y = __builtin_nontemporal_load(f + 1);
  sh8 r;
  r[0] = (short)f2bf(x[0]); r[1] = (short)f2bf(x[1]);
  r[2] = (short)f2bf(x[2]); r[3] = (short)f2bf(x[3]);
  r[4] = (short)f2bf(y[0]); r[5] = (short)f2bf(y[1]);
  r[6] = (short)f2bf(y[2]); r[7] = (short)f2bf(y[3]);
  return r;
}

// ---------------- prep + degree count (R7: k_count fused; cnt pre-zeroed) ---
__global__ void k_prep(const float* __restrict__ Ws, const float* __restrict__ Wn,
                       const float* __restrict__ Wm, const float* __restrict__ Wg,
                       const float* __restrict__ b_sage, const float* __restrict__ bg,
                       const float* __restrict__ bm, const float* __restrict__ ln_g,
                       const float* __restrict__ ln_b, const int* __restrict__ dst,
                       u16* __restrict__ WmT, u16* __restrict__ WsT, u16* __restrict__ WnT,
                       u16* __restrict__ WsgT, u16* __restrict__ WngT, u16* __restrict__ WgBT,
                       float* __restrict__ bm_f, float* __restrict__ lng_f,
                       float* __restrict__ lnb_f, float* __restrict__ bsage_f,
                       float* __restrict__ bsg, int* __restrict__ cnt, int E) {
  int idx = blockIdx.x * blockDim.x + threadIdx.x;
  int stride = gridDim.x * blockDim.x;
  for (int i = idx; i < 32768; i += stride) {
    int n = i >> 8, k = i & 255;
    WmT[n * 256 + k] = f2bf(Wm[k * 128 + n]);
  }
  for (int i = idx; i < 16384; i += stride) {
    int n = i >> 7, k = i & 127;
    WsT[i] = f2bf(Ws[k * 128 + n]);
    WnT[i] = f2bf(Wn[k * 128 + n]);
    WgBT[i] = f2bf(Wg[(128 + k) * 128 + n]);
  }
  for (int i = idx; i < 16384; i += stride) {
    int c = i >> 7, k = i & 127;
    float s1 = 0.f, s2 = 0.f;
    for (int j = 0; j < 128; ++j) {
      float wg = Wg[j * 128 + c];
      s1 += Ws[k * 128 + j] * wg;
      s2 += Wn[k * 128 + j] * wg;
    }
    WsgT[c * 128 + k] = f2bf(s1);
    WngT[c * 128 + k] = f2bf(s2);
  }
  for (int i = idx; i < 128; i += stride) {
    bm_f[i] = bm[i];
    lng_f[i] = ln_g[i];
    lnb_f[i] = ln_b[i];
    bsage_f[i] = b_sage[i];
    float s = bg[i];
    for (int j = 0; j < 128; ++j) s += b_sage[j] * Wg[j * 128 + i];
    bsg[i] = s;
  }
  // degree count (cnt zeroed by stream-ordered memset before this kernel)
  for (int e = idx; e < E; e += stride) atomicAdd(&cnt[dst[e]], 1);
}

// ---------------- CSR build: 2-kernel scan + perm ---------------------------
__global__ void k_scan1(const int* __restrict__ cnt, int* __restrict__ bsum, int N) {
  int i = blockIdx.x * 256 + threadIdx.x;
  int v = (i < N) ? cnt[i] : 0;
#pragma unroll
  for (int m = 1; m < 64; m <<= 1) v += __shfl_xor(v, m, 64);
  __shared__ int ws[4];
  if ((threadIdx.x & 63) == 0) ws[threadIdx.x >> 6] = v;
  __syncthreads();
  if (threadIdx.x == 0) bsum[blockIdx.x] = ws[0] + ws[1] + ws[2] + ws[3];
}

// R7: scan2 fused in — each block computes its own chunk-prefix from bsum.
__global__ void k_scan23(const int* __restrict__ cnt, const int* __restrict__ bsum,
                         int* __restrict__ rowptr, int* __restrict__ cursor, int N) {
  __shared__ int ws2[4];
  __shared__ int s[256];
  int t = threadIdx.x;
  int c = blockIdx.x;
  int base = 0;
  for (int j = t; j < c; j += 256) base += bsum[j];
#pragma unroll
  for (int m = 1; m < 64; m <<= 1) base += __shfl_xor(base, m, 64);
  if ((t & 63) == 0) ws2[t >> 6] = base;
  __syncthreads();
  base = ws2[0] + ws2[1] + ws2[2] + ws2[3];
  int i = c * 256 + t;
  int v = (i < N) ? cnt[i] : 0;
  s[t] = v;
  __syncthreads();
  for (int off = 1; off < 256; off <<= 1) {
    int x = (t >= off) ? s[t - off] : 0;
    __syncthreads();
    s[t] += x;
    __syncthreads();
  }
  int excl = base + s[t] - v;
  if (i < N) {
    rowptr[i] = excl;
    cursor[i] = excl;
    if (i == N - 1) rowptr[N] = excl + v;
  }
}

__global__ void k_perm(const int* __restrict__ src, const int* __restrict__ dst,
                       int* __restrict__ cursor, int* __restrict__ src_sorted, int E) {
  int e = blockIdx.x * blockDim.x + threadIdx.x;
  if (e < E) {
    int p = atomicAdd(&cursor[dst[e]], 1);
    src_sorted[p] = src[e];
  }
}

// ---------------- node MLP: M = relu(LN(concat(h,ctx)@Wm + bm)) -------------
// R3 structure (verified): weights in VGPRs (A), node tile in 8KB LDS (B).
__global__ __launch_bounds__(512) void k_node(
    const float* __restrict__ h, const float* __restrict__ ctx,
    const u16* __restrict__ WmT, const float* __restrict__ bm_f,
    const float* __restrict__ lng_f, const float* __restrict__ lnb_f,
    u16* __restrict__ hm, int N) {
  __shared__ u16 atile[16 * 256];
  __shared__ u16 mtile[16 * 128];
  __shared__ float scr[8 * 16 * 2];
  int tid = threadIdx.x;
  int lane = tid & 63;
  int wave = tid >> 6;
  int col16 = lane & 15;
  int quad = lane >> 4;

  sh8 areg[8];
#pragma unroll
  for (int ks = 0; ks < 8; ++ks)
    areg[ks] = *(const sh8*)&WmT[(size_t)(wave * 16 + col16) * 256 + ks * 32 + quad * 8];

  float bmv[4], gv[4], bv[4];
#pragma unroll
  for (int r = 0; r < 4; ++r) {
    int c = wave * 16 + quad * 4 + r;
    bmv[r] = bm_f[c]; gv[r] = lng_f[c]; bv[r] = lnb_f[c];
  }

  int srow = tid >> 5;
  int c8 = tid & 31;
  int TT = (N + 15) >> 4;
  for (int tile = blockIdx.x; tile < TT; tile += gridDim.x) {
    int n0 = tile * 16;
    {
      int node = min(n0 + srow, N - 1);
      sh8 a = (c8 < 16) ? load8f_nt(h, (size_t)node * 128 + c8 * 8)
                        : load8f_nt(ctx, (size_t)node * 128 + (c8 - 16) * 8);
      *(sh8*)&atile[srow * 256 + ((c8 ^ (srow & 7)) << 3)] = a;
      if (c8 < 16 && n0 + srow < N)
        __builtin_nontemporal_store(a, (sh8*)&hm[(size_t)(n0 + srow) * 256 + c8 * 8]);
    }
    __syncthreads();
    f32x4 acc = (f32x4)0.0f;
#pragma unroll
    for (int ks = 0; ks < 8; ++ks) {
      int chunk = ks * 4 + quad;
      sh8 b = *(const sh8*)&atile[col16 * 256 + ((chunk ^ (col16 & 7)) << 3)];
      acc = __builtin_amdgcn_mfma_f32_16x16x32_bf16(areg[ks], b, acc, 0, 0, 0);
    }
    float v[4], s1 = 0.f, s2 = 0.f;
#pragma unroll
    for (int r = 0; r < 4; ++r) {
      v[r] = acc[r] + bmv[r];
      s1 += v[r]; s2 += v[r] * v[r];
    }
    s1 += __shfl_xor(s1, 16, 64); s2 += __shfl_xor(s2, 16, 64);
    s1 += __shfl_xor(s1, 32, 64); s2 += __shfl_xor(s2, 32, 64);
    if (lane < 16) {
      scr[(wave * 16 + lane) * 2 + 0] = s1;
      scr[(wave * 16 + lane) * 2 + 1] = s2;
    }
    __syncthreads();
    float t1 = 0.f, t2 = 0.f;
#pragma unroll
    for (int w2 = 0; w2 < 8; ++w2) {
      t1 += scr[(w2 * 16 + col16) * 2 + 0];
      t2 += scr[(w2 * 16 + col16) * 2 + 1];
    }
    float mu = t1 * (1.f / 128.f);
    float var = t2 * (1.f / 128.f) - mu * mu;
    float rstd = rsqrtf(fmaxf(var, 0.f) + 1e-5f);
    us4 pk;
#pragma unroll
    for (int r = 0; r < 4; ++r) {
      float x = (v[r] - mu) * rstd * gv[r] + bv[r];
      x = x > 0.f ? x : 0.f;
      pk[r] = f2bf(x);
    }
    *(us4*)&mtile[col16 * 128 + wave * 16 + quad * 4] = pk;
    __syncthreads();
    if (tid < 256) {
      int row = tid >> 4, ch = tid & 15;
      if (n0 + row < N) {
        sh8 mv = *(const sh8*)&mtile[row * 128 + ch * 8];
        __builtin_nontemporal_store(mv, (sh8*)&hm[(size_t)(n0 + row) * 256 + 128 + ch * 8]);
      }
    }
  }
}

// ---------------- per-node aggregation over hm rows -------------------------
// Lane-split (R5) + 8-edge batch (R6). ~43us = L3 random-gather service
// floor (R5/R6 width/ILP probes both null).
__global__ __launch_bounds__(256) void k_agg(
    const u16* __restrict__ hm, const int* __restrict__ rowptr,
    const int* __restrict__ src_sorted,
    u16* __restrict__ nm, u16* __restrict__ cagg, int N) {
  int gw = (blockIdx.x * 256 + threadIdx.x) >> 6;
  int lane = threadIdx.x & 63;
  int half = lane >> 5;
  int cl = lane & 31;
  int tw = (gridDim.x * 256) >> 6;
  for (int n = gw; n < N; n += tw) {
    int b = rowptr[n], e = rowptr[n + 1];
    float a0 = 0.f, a1 = 0.f, a2 = 0.f, a3 = 0.f;
    float a4 = 0.f, a5 = 0.f, a6 = 0.f, a7 = 0.f;
    int i = b;
    for (; i + 8 <= e; i += 8) {
      int s0 = src_sorted[i + half];
      int s1 = src_sorted[i + 2 + half];
      int s2 = src_sorted[i + 4 + half];
      int s3 = src_sorted[i + 6 + half];
      sh8 v0 = *(const sh8*)(hm + (size_t)s0 * 256 + (cl << 3));
      sh8 v1 = *(const sh8*)(hm + (size_t)s1 * 256 + (cl << 3));
      sh8 v2 = *(const sh8*)(hm + (size_t)s2 * 256 + (cl << 3));
      sh8 v3 = *(const sh8*)(hm + (size_t)s3 * 256 + (cl << 3));
      a0 += bf2f((u16)v0[0]) + bf2f((u16)v1[0]) + bf2f((u16)v2[0]) + bf2f((u16)v3[0]);
      a1 += bf2f((u16)v0[1]) + bf2f((u16)v1[1]) + bf2f((u16)v2[1]) + bf2f((u16)v3[1]);
      a2 += bf2f((u16)v0[2]) + bf2f((u16)v1[2]) + bf2f((u16)v2[2]) + bf2f((u16)v3[2]);
      a3 += bf2f((u16)v0[3]) + bf2f((u16)v1[3]) + bf2f((u16)v2[3]) + bf2f((u16)v3[3]);
      a4 += bf2f((u16)v0[4]) + bf2f((u16)v1[4]) + bf2f((u16)v2[4]) + bf2f((u16)v3[4]);
      a5 += bf2f((u16)v0[5]) + bf2f((u16)v1[5]) + bf2f((u16)v2[5]) + bf2f((u16)v3[5]);
      a6 += bf2f((u16)v0[6]) + bf2f((u16)v1[6]) + bf2f((u16)v2[6]) + bf2f((u16)v3[6]);
      a7 += bf2f((u16)v0[7]) + bf2f((u16)v1[7]) + bf2f((u16)v2[7]) + bf2f((u16)v3[7]);
    }
    for (; i + 4 <= e; i += 4) {
      int s0 = src_sorted[i + half];
      int s1 = src_sorted[i + 2 + half];
      sh8 v0 = *(const sh8*)(hm + (size_t)s0 * 256 + (cl << 3));
      sh8 v1 = *(const sh8*)(hm + (size_t)s1 * 256 + (cl << 3));
      a0 += bf2f((u16)v0[0]) + bf2f((u16)v1[0]);
      a1 += bf2f((u16)v0[1]) + bf2f((u16)v1[1]);
      a2 += bf2f((u16)v0[2]) + bf2f((u16)v1[2]);
      a3 += bf2f((u16)v0[3]) + bf2f((u16)v1[3]);
      a4 += bf2f((u16)v0[4]) + bf2f((u16)v1[4]);
      a5 += bf2f((u16)v0[5]) + bf2f((u16)v1[5]);
      a6 += bf2f((u16)v0[6]) + bf2f((u16)v1[6]);
      a7 += bf2f((u16)v0[7]) + bf2f((u16)v1[7]);
    }
    for (; i + 2 <= e; i += 2) {
      int s0 = src_sorted[i + half];
      sh8 v0 = *(const sh8*)(hm + (size_t)s0 * 256 + (cl << 3));
      a0 += bf2f((u16)v0[0]); a1 += bf2f((u16)v0[1]);
      a2 += bf2f((u16)v0[2]); a3 += bf2f((u16)v0[3]);
      a4 += bf2f((u16)v0[4]); a5 += bf2f((u16)v0[5]);
      a6 += bf2f((u16)v0[6]); a7 += bf2f((u16)v0[7]);
    }
    if (i < e && half == 0) {
      int s0 = src_sorted[i];
      sh8 v0 = *(const sh8*)(hm + (size_t)s0 * 256 + (cl << 3));
      a0 += bf2f((u16)v0[0]); a1 += bf2f((u16)v0[1]);
      a2 += bf2f((u16)v0[2]); a3 += bf2f((u16)v0[3]);
      a4 += bf2f((u16)v0[4]); a5 += bf2f((u16)v0[5]);
      a6 += bf2f((u16)v0[6]); a7 += bf2f((u16)v0[7]);
    }
    a0 += __shfl_xor(a0, 32, 64); a1 += __shfl_xor(a1, 32, 64);
    a2 += __shfl_xor(a2, 32, 64); a3 += __shfl_xor(a3, 32, 64);
    a4 += __shfl_xor(a4, 32, 64); a5 += __shfl_xor(a5, 32, 64);
    a6 += __shfl_xor(a6, 32, 64); a7 += __shfl_xor(a7, 32, 64);
    if (half == 0) {
      float inv = (e > b) ? 1.f / (float)(e - b) : 0.f;
      sh8 p;
      p[0] = (short)f2bf(a0 * inv); p[1] = (short)f2bf(a1 * inv);
      p[2] = (short)f2bf(a2 * inv); p[3] = (short)f2bf(a3 * inv);
      p[4] = (short)f2bf(a4 * inv); p[5] = (short)f2bf(a5 * inv);
      p[6] = (short)f2bf(a6 * inv); p[7] = (short)f2bf(a7 * inv);
      if (cl < 16)
        *(sh8*)(nm + (size_t)n * 128 + (cl << 3)) = p;
      else
        *(sh8*)(cagg + (size_t)n * 128 + ((cl - 16) << 3)) = p;
    }
  }
}

// ---------------- fused node GEMMs + gate + blend (4-way col-split) ---------
// R7: XCD-aware bid swizzle. The 4 q-variants of one tile-range read the
// SAME hm/nm/cagg rows; map them to the same XCD (same bid&7 under round-
// robin dispatch) so 3 of 4 reads hit that XCD's L2. Bijective for grid=1024.
__global__ __launch_bounds__(256, 3) void k_out(
    const u16* __restrict__ hm, const u16* __restrict__ nm, const u16* __restrict__ cagg,
    const u16* __restrict__ WsT, const u16* __restrict__ WnT,
    const u16* __restrict__ WsgT, const u16* __restrict__ WngT, const u16* __restrict__ WgBT,
    const float* __restrict__ bsage_f, const float* __restrict__ bsg,
    float* __restrict__ out, int N) {
  __shared__ u16 blds[5 * 32 * 128];  // 40 KB
  int tid = threadIdx.x;
  int bid = blockIdx.x;
  int q = (bid >> 3) & 3;                       // col group, same XCD for all 4
  int tg = (bid & 7) | ((bid >> 5) << 3);       // tile-group 0..255
  {
    const u16* matp[5] = {WsT, WnT, WsgT, WngT, WgBT};
#pragma unroll
    for (int m = 0; m < 5; ++m) {
#pragma unroll
      for (int j = 0; j < 2; ++j) {
        int f = tid + j * 256;
        int lc = f >> 4, kc = f & 15;
        int kcs = kc ^ (lc & 15);
        *(sh8*)&blds[(m * 32 + lc) * 128 + kcs * 8] =
            *(const sh8*)&matp[m][(size_t)(q * 32 + lc) * 128 + kc * 8];
      }
    }
  }
  __syncthreads();
  int lane = tid & 63;
  int wave = tid >> 6;
  int col = lane & 15, quad = lane >> 4;
  float bsv[2], bgv[2];
#pragma unroll
  for (int tt = 0; tt < 2; ++tt) {
    int gc = q * 32 + tt * 16 + col;
    bsv[tt] = bsage_f[gc];
    bgv[tt] = bsg[gc];
  }
  int TT = (N + 15) >> 4;
  int slots = (gridDim.x >> 2) * 4;
  for (int tile = tg * 4 + wave; tile < TT; tile += slots) {
    int nr = min(tile * 16 + col, N - 1);
    f32x4 as[2], ag[2];
#pragma unroll
    for (int tt = 0; tt < 2; ++tt) {
      as[tt] = (f32x4)0.0f;
      ag[tt] = (f32x4)0.0f;
    }
#pragma unroll 1
    for (int ks = 0; ks < 4; ++ks) {
      int k = ks * 32 + quad * 8;
      sh8 ah = *(const sh8*)&hm[(size_t)nr * 256 + k];
      sh8 am = *(const sh8*)&nm[(size_t)nr * 128 + k];
      sh8 ac = *(const sh8*)&cagg[(size_t)nr * 128 + k];
      int kcs8 = ((ks * 4 + quad) ^ col) * 8;
#pragma unroll
      for (int tt = 0; tt < 2; ++tt) {
        int lc = tt * 16 + col;
        sh8 b1 = *(const sh8*)&blds[(0 * 32 + lc) * 128 + kcs8];
        sh8 b2 = *(const sh8*)&blds[(1 * 32 + lc) * 128 + kcs8];
        sh8 b3 = *(const sh8*)&blds[(2 * 32 + lc) * 128 + kcs8];
        sh8 b4 = *(const sh8*)&blds[(3 * 32 + lc) * 128 + kcs8];
        sh8 b5 = *(const sh8*)&blds[(4 * 32 + lc) * 128 + kcs8];
        as[tt] = __builtin_amdgcn_mfma_f32_16x16x32_bf16(ah, b1, as[tt], 0, 0, 0);
        as[tt] = __builtin_amdgcn_mfma_f32_16x16x32_bf16(am, b2, as[tt], 0, 0, 0);
        ag[tt] = __builtin_amdgcn_mfma_f32_16x16x32_bf16(ah, b3, ag[tt], 0, 0, 0);
        ag[tt] = __builtin_amdgcn_mfma_f32_16x16x32_bf16(am, b4, ag[tt], 0, 0, 0);
        ag[tt] = __builtin_amdgcn_mfma_f32_16x16x32_bf16(ac, b5, ag[tt], 0, 0, 0);
      }
    }
#pragma unroll
    for (int r = 0; r < 4; ++r) {
      int n = tile * 16 + quad * 4 + r;
      if (n < N) {
#pragma unroll
        for (int tt = 0; tt < 2; ++tt) {
          int gc = q * 32 + tt * 16 + col;
          float sv = as[tt][r] + bsv[tt];
          float gl = ag[tt][r] + bgv[tt];
          float g = 1.f / (1.f + __expf(-gl));
          float ca = bf2f(cagg[(size_t)n * 128 + gc]);
          __builtin_nontemporal_store(g * sv + (1.f - g) * ca,
                                      &out[(size_t)n * 128 + gc]);
        }
      }
    }
  }
}

extern "C" void kernel_launch(void* const* d_in, const int* in_sizes, int n_in,
                              void* d_out, int out_size, void* d_ws, size_t ws_size,
                              hipStream_t stream) {
  const float* h = (const float*)d_in[0];
  const float* ctx = (const float*)d_in[1];
  const int* src = (const int*)d_in[2];
  const int* dst = (const int*)d_in[3];
  const float* Ws = (const float*)d_in[4];
  const float* Wn = (const float*)d_in[5];
  const float* b_sage = (const float*)d_in[6];
  const float* Wm = (const float*)d_in[7];
  const float* bm = (const float*)d_in[8];
  const float* ln_g = (const float*)d_in[9];
  const float* ln_b = (const float*)d_in[10];
  const float* Wg = (const float*)d_in[11];
  const float* bg = (const float*)d_in[12];
  int N = in_sizes[0] / 128;
  int E = in_sizes[2];

  char* w = (char*)d_ws;
  auto carve = [&](size_t bytes) {
    char* p = w;
    w += (bytes + 255) & ~(size_t)255;
    return p;
  };
  int* cnt = (int*)carve((size_t)N * 4);
  int* rowptr = (int*)carve((size_t)(N + 1) * 4);
  int* cursor = (int*)carve((size_t)N * 4);
  int* src_sorted = (int*)carve((size_t)E * 4);
  int NB = (N + 255) / 256;
  int* bsum = (int*)carve((size_t)NB * 4);
  u16* WmT = (u16*)carve(32768 * 2);
  u16* WsT = (u16*)carve(16384 * 2);
  u16* WnT = (u16*)carve(16384 * 2);
  u16* WsgT = (u16*)carve(16384 * 2);
  u16* WngT = (u16*)carve(16384 * 2);
  u16* WgBT = (u16*)carve(16384 * 2);
  float* bm_f = (float*)carve(128 * 4);
  float* lng_f = (float*)carve(128 * 4);
  float* lnb_f = (float*)carve(128 * 4);
  float* bsage_f = (float*)carve(128 * 4);
  float* bsg = (float*)carve(128 * 4);
  u16* hm = (u16*)carve((size_t)N * 256 * 2);
  u16* nm = (u16*)carve((size_t)N * 128 * 2);
  u16* cagg = (u16*)carve((size_t)N * 128 * 2);

  hipMemsetAsync(cnt, 0, (size_t)N * 4, stream);
  k_prep<<<256, 256, 0, stream>>>(Ws, Wn, Wm, Wg, b_sage, bg, bm, ln_g, ln_b, dst,
                                  WmT, WsT, WnT, WsgT, WngT, WgBT,
                                  bm_f, lng_f, lnb_f, bsage_f, bsg, cnt, E);
  k_scan1<<<NB, 256, 0, stream>>>(cnt, bsum, N);
  k_scan23<<<NB, 256, 0, stream>>>(cnt, bsum, rowptr, cursor, N);
  k_perm<<<(E + 255) / 256, 256, 0, stream>>>(src, dst, cursor, src_sorted, E);
  int TT = (N + 15) / 16;
  int gn = TT < 1024 ? TT : 1024;
  k_node<<<gn, 512, 0, stream>>>(h, ctx, WmT, bm_f, lng_f, lnb_f, hm, N);
  k_agg<<<4096, 256, 0, stream>>>(hm, rowptr, src_sorted, nm, cagg, N);
  k_out<<<1024, 256, 0, stream>>>(hm, nm, cagg, WsT, WnT, WsgT, WngT, WgBT,
                                  bsage_f, bsg, (float*)d_out, N);
}